// Round 4
// baseline (398.644 us; speedup 1.0000x reference)
//
#include <hip/hip_runtime.h>
#include <hip/hip_bf16.h>

// Problem constants: B=2, N=2048, C=1024, H=16, hd=64. All inputs/output fp32.
#define SEQ   2048
#define CDIM  1024

typedef short short8  __attribute__((ext_vector_type(8)));
typedef short short4v __attribute__((ext_vector_type(4)));
typedef float floatx4 __attribute__((ext_vector_type(4)));

__device__ __forceinline__ float bf2f(unsigned short h) {
    unsigned int u = ((unsigned int)h) << 16;
    float f; __builtin_memcpy(&f, &u, 4); return f;
}
__device__ __forceinline__ unsigned short f2bf(float f) {
    unsigned int u; __builtin_memcpy(&u, &f, 4);
    u += 0x7fffu + ((u >> 16) & 1u);   // RNE
    return (unsigned short)(u >> 16);
}

// ---------------------------------------------------------------------------
// fp32 -> bf16 conversion, two arrays per launch (second may be empty).
// Memory-bound grid-stride over float4 chunks.
// ---------------------------------------------------------------------------
__global__ __launch_bounds__(256) void cvt2(
    const float* __restrict__ a, unsigned short* __restrict__ da, int na4,
    const float* __restrict__ b, unsigned short* __restrict__ db, int nb4)
{
    int total = na4 + nb4;
    for (int i = blockIdx.x * 256 + threadIdx.x; i < total; i += gridDim.x * 256) {
        const float* src; unsigned short* dst; int j;
        if (i < na4) { src = a; dst = da; j = i; }
        else         { src = b; dst = db; j = i - na4; }
        floatx4 v = ((const floatx4*)src)[j];
        short4v o;
        o[0] = f2bf(v[0]); o[1] = f2bf(v[1]); o[2] = f2bf(v[2]); o[3] = f2bf(v[3]);
        ((short4v*)dst)[j] = o;
    }
}

// ---------------------------------------------------------------------------
// GEMM: C[m][n] = sum_k A[m][k]*B[n][k] (+bias[n]). bf16 in, fp32 acc.
// m97 structure: 128x128 tile, BK=32, unpadded LDS, global_load_lds width=16.
// ---------------------------------------------------------------------------
template <bool OUT_F32>
__global__ __launch_bounds__(256) void gemm_bt(
    const unsigned short* __restrict__ A,
    const unsigned short* __restrict__ B,
    const float* __restrict__ bias,
    void* __restrict__ C,
    int Ndim, int Kdim, int use_bias)
{
    __shared__ unsigned short As[128][32];
    __shared__ unsigned short Bs[128][32];

    const int tid  = threadIdx.x;
    const int lane = tid & 63, wave = tid >> 6;
    const int wr = (wave >> 1) * 64, wc = (wave & 1) * 64;
    const int lrow = lane & 15, quad = lane >> 4;
    const int m0 = blockIdx.y * 128, n0 = blockIdx.x * 128;

    const int ako = (lane & 3) * 8;            // k-offset within BK for staging
    floatx4 acc[4][4] = {};

    for (int k0 = 0; k0 < Kdim; k0 += 32) {
        __syncthreads();
        #pragma unroll
        for (int j = 0; j < 2; ++j) {
            int rbase = (wave * 2 + j) * 16;
            int row   = rbase + (lane >> 2);
            __builtin_amdgcn_global_load_lds(
                (const __attribute__((address_space(1))) void*)(A + (size_t)(m0 + row) * Kdim + k0 + ako),
                (__attribute__((address_space(3))) void*)&As[rbase][0], 16, 0, 0);
            __builtin_amdgcn_global_load_lds(
                (const __attribute__((address_space(1))) void*)(B + (size_t)(n0 + row) * Kdim + k0 + ako),
                (__attribute__((address_space(3))) void*)&Bs[rbase][0], 16, 0, 0);
        }
        __syncthreads();   // drains vmcnt(0) -> LDS valid

        short8 af[4], bf[4];
        #pragma unroll
        for (int mi = 0; mi < 4; ++mi) af[mi] = *(const short8*)&As[wr + mi * 16 + lrow][quad * 8];
        #pragma unroll
        for (int ni = 0; ni < 4; ++ni) bf[ni] = *(const short8*)&Bs[wc + ni * 16 + lrow][quad * 8];
        #pragma unroll
        for (int mi = 0; mi < 4; ++mi)
            #pragma unroll
            for (int ni = 0; ni < 4; ++ni)
                acc[mi][ni] = __builtin_amdgcn_mfma_f32_16x16x32_bf16(af[mi], bf[ni], acc[mi][ni], 0, 0, 0);
    }

    // C/D layout: col = lane&15, row = quad*4 + r
    #pragma unroll
    for (int mi = 0; mi < 4; ++mi) {
        #pragma unroll
        for (int r = 0; r < 4; ++r) {
            int row = m0 + wr + mi * 16 + quad * 4 + r;
            #pragma unroll
            for (int ni = 0; ni < 4; ++ni) {
                int col = n0 + wc + ni * 16 + lrow;
                float v = acc[mi][ni][r];
                if (use_bias) v += bias[col];
                if (OUT_F32) ((float*)C)[(size_t)row * Ndim + col] = v;
                else ((unsigned short*)C)[(size_t)row * Ndim + col] = f2bf(v);
            }
        }
    }
}

// ---------------------------------------------------------------------------
// Per-(token,head) RMSNorm + RoPE. One wave per (m,h), lane = head dim.
// qkv (bf16) row: [q(1024)|k(1024)|v(1024)]. Writes Q,K [bh][n][64];
// V transposed [bh][64][n] (PV B-operand needs key-contiguous layout).
// ---------------------------------------------------------------------------
__global__ __launch_bounds__(256) void norm_rope(
    const unsigned short* __restrict__ qkv,
    const float* __restrict__ fc,
    const float* __restrict__ fs,
    const float* __restrict__ qg,
    const float* __restrict__ kg,
    unsigned short* __restrict__ Q,
    unsigned short* __restrict__ K,
    unsigned short* __restrict__ Vt)
{
    int gid  = blockIdx.x * 4 + (threadIdx.x >> 6);
    int lane = threadIdx.x & 63;
    int h = gid & 15, m = gid >> 4;
    int b = m >> 11, n = m & 2047;

    const unsigned short* row = qkv + (size_t)m * 3072;
    float q = bf2f(row[h * 64 + lane]);
    float k = bf2f(row[1024 + h * 64 + lane]);
    float v = bf2f(row[2048 + h * 64 + lane]);

    float q2 = q * q, k2 = k * k;
    #pragma unroll
    for (int off = 32; off; off >>= 1) {
        q2 += __shfl_xor(q2, off);
        k2 += __shfl_xor(k2, off);
    }
    q = q * (8.0f / fmaxf(sqrtf(q2), 1e-12f)) * qg[lane];
    k = k * (8.0f / fmaxf(sqrtf(k2), 1e-12f)) * kg[lane];

    float c = fc[(size_t)m * 64 + lane];
    float s = fs[(size_t)m * 64 + lane];
    float qp = __shfl_xor(q, 1), kp = __shfl_xor(k, 1);
    float qr = (lane & 1) ? qp : -qp;
    float kr = (lane & 1) ? kp : -kp;
    q = q * c + qr * s;
    k = k * c + kr * s;

    int bh = b * 16 + h;
    Q[((size_t)bh * SEQ + n) * 64 + lane] = f2bf(q);
    K[((size_t)bh * SEQ + n) * 64 + lane] = f2bf(k);
    Vt[((size_t)bh * 64 + lane) * SEQ + n] = f2bf(v);
}

// ---------------------------------------------------------------------------
// Flash attention, S^T formulation. Block = (qt, bh): 64 q-rows. 4 waves,
// each owns 16 q-rows. 128-key tiles, online softmax with per-lane q-rows.
// mfma(kf, qf) -> S^T: lane holds S[key=ni*16+quad*4+r][q=q0+(lane&15)],
// so softmax reductions are in-lane + 2 shfl_xor, mask loads are float4.
// ---------------------------------------------------------------------------
__global__ __launch_bounds__(256) void attn(
    const unsigned short* __restrict__ Q,
    const unsigned short* __restrict__ K,
    const unsigned short* __restrict__ Vt,
    const float* __restrict__ mask,
    unsigned short* __restrict__ O)
{
    __shared__ unsigned short Ks[128][72];     // [key][d], +8 pad
    __shared__ unsigned short Vs[64][136];     // [d][key], +8 pad
    __shared__ unsigned short Ps[4][16][136];  // per-wave P, [q][key], +8 pad

    const int tid = threadIdx.x, lane = tid & 63, wave = tid >> 6;
    const int lrow = lane & 15, quad = lane >> 4;
    const int qt = blockIdx.x, bh = blockIdx.y;
    const int b = bh >> 4, h = bh & 15;
    const int q0 = qt * 64 + wave * 16;
    const float scale = 0.125f;   // 64^-0.5

    const unsigned short* Qb = Q + (size_t)bh * SEQ * 64;
    const unsigned short* Kb = K + (size_t)bh * SEQ * 64;
    const unsigned short* Vb = Vt + (size_t)bh * 64 * SEQ;
    const float* mrow = mask + (size_t)(q0 + lrow) * SEQ;   // this lane's q-row

    // Q frags (B-operand): [n=lane&15=q][k=quad*8+j], two 32-wide k-steps
    short8 qf[2];
    #pragma unroll
    for (int ks = 0; ks < 2; ++ks)
        qf[ks] = *(const short8*)(Qb + (size_t)(q0 + lrow) * 64 + ks * 32 + quad * 8);

    float m_i = -1e30f, l_i = 0.f;
    floatx4 oacc[4] = {};

    for (int kt = 0; kt < 16; ++kt) {
        __syncthreads();
        #pragma unroll
        for (int i = 0; i < 4; ++i) {          // Ks: 1024 chunks of 8 bf16
            int c = tid + i * 256;
            int kr = c >> 3, ko = (c & 7) * 8;
            *(short8*)&Ks[kr][ko] = *(const short8*)(Kb + (size_t)(kt * 128 + kr) * 64 + ko);
        }
        #pragma unroll
        for (int i = 0; i < 4; ++i) {          // Vs: 1024 chunks of 8 bf16
            int c = tid + i * 256;
            int vr = c >> 4, ko = (c & 15) * 8;
            *(short8*)&Vs[vr][ko] = *(const short8*)(Vb + (size_t)vr * SEQ + kt * 128 + ko);
        }
        __syncthreads();

        // S^T = K @ Q^T : s[ni][r] = S[key=ni*16+quad*4+r][q]
        floatx4 s[8];
        #pragma unroll
        for (int ni = 0; ni < 8; ++ni) {
            s[ni] = floatx4{0.f, 0.f, 0.f, 0.f};
            #pragma unroll
            for (int ks = 0; ks < 2; ++ks) {
                short8 kf = *(const short8*)&Ks[ni * 16 + lrow][ks * 32 + quad * 8];
                s[ni] = __builtin_amdgcn_mfma_f32_16x16x32_bf16(kf, qf[ks], s[ni], 0, 0, 0);
            }
        }

        // scale + mask (vector float4: 4 consecutive keys per lane)
        float mt = -1e30f;
        #pragma unroll
        for (int ni = 0; ni < 8; ++ni) {
            floatx4 mk = *(const floatx4*)(mrow + kt * 128 + ni * 16 + quad * 4);
            #pragma unroll
            for (int r = 0; r < 4; ++r) {
                s[ni][r] = s[ni][r] * scale + mk[r];
                mt = fmaxf(mt, s[ni][r]);
            }
        }
        mt = fmaxf(mt, __shfl_xor(mt, 16));
        mt = fmaxf(mt, __shfl_xor(mt, 32));

        float mn = fmaxf(m_i, mt);
        float alpha = __expf(m_i - mn);
        m_i = mn;
        float rs = 0.f;
        #pragma unroll
        for (int ni = 0; ni < 8; ++ni)
            #pragma unroll
            for (int r = 0; r < 4; ++r) {
                float p = __expf(s[ni][r] - mn);
                s[ni][r] = p;
                rs += p;
            }
        rs += __shfl_xor(rs, 16);
        rs += __shfl_xor(rs, 32);
        l_i = l_i * alpha + rs;

        // P^T -> LDS [q][key], b64 packed (4 consecutive keys)
        #pragma unroll
        for (int ni = 0; ni < 8; ++ni) {
            short4v pk;
            pk[0] = f2bf(s[ni][0]); pk[1] = f2bf(s[ni][1]);
            pk[2] = f2bf(s[ni][2]); pk[3] = f2bf(s[ni][3]);
            *(short4v*)&Ps[wave][lrow][ni * 16 + quad * 4] = pk;
        }

        // rescale O by alpha of its rows (oacc row q = q0+quad*4+r; alpha
        // lives at lanes with lrow == quad*4+r, identical across quads)
        #pragma unroll
        for (int r = 0; r < 4; ++r) {
            float ar = __shfl(alpha, quad * 4 + r);
            #pragma unroll
            for (int ni = 0; ni < 4; ++ni) oacc[ni][r] *= ar;
        }

        // O += P @ V. Wave-private Ps: in-wave lgkmcnt ordering, no barrier.
        short8 pa[4];
        #pragma unroll
        for (int ks = 0; ks < 4; ++ks)
            pa[ks] = *(const short8*)&Ps[wave][lrow][ks * 32 + quad * 8];
        #pragma unroll
        for (int ni = 0; ni < 4; ++ni)
            #pragma unroll
            for (int ks = 0; ks < 4; ++ks) {
                short8 vb = *(const short8*)&Vs[ni * 16 + lrow][ks * 32 + quad * 8];
                oacc[ni] = __builtin_amdgcn_mfma_f32_16x16x32_bf16(pa[ks], vb, oacc[ni], 0, 0, 0);
            }
    }

    // epilogue: fetch denom for row q0+quad*4+r from lane lrow==quad*4+r
    float inv[4];
    #pragma unroll
    for (int r = 0; r < 4; ++r) inv[r] = 1.0f / __shfl(l_i, quad * 4 + r);
    #pragma unroll
    for (int r = 0; r < 4; ++r) {
        int row = q0 + quad * 4 + r;
        #pragma unroll
        for (int ni = 0; ni < 4; ++ni) {
            int col = ni * 16 + lrow;
            O[((size_t)(b * SEQ + row)) * CDIM + h * 64 + col] = f2bf(oacc[ni][r] * inv[r]);
        }
    }
}

// ---------------------------------------------------------------------------
extern "C" void kernel_launch(void* const* d_in, const int* in_sizes, int n_in,
                              void* d_out, int out_size, void* d_ws, size_t ws_size,
                              hipStream_t stream)
{
    const float* x      = (const float*)d_in[0];
    const float* fc     = (const float*)d_in[1];
    const float* fs     = (const float*)d_in[2];
    const float* mask   = (const float*)d_in[3];
    const float* w_qkv  = (const float*)d_in[4];
    const float* w_proj = (const float*)d_in[5];
    const float* b_proj = (const float*)d_in[6];
    const float* qg     = (const float*)d_in[7];
    const float* kg     = (const float*)d_in[8];

    // workspace (48 MB high-water, same as round 3):
    //   xb     @0         8 MB  (x bf16)          dead after gemm1
    //   wqkvb  @8 MB      6 MB  (w_qkv bf16)      dead after gemm1
    //   qkv    @16 MB    24 MB  (gemm1 out)       dead after norm_rope
    //   Q      @0         8 MB  (over dead xb)
    //   K      @8 MB      8 MB  (over dead wqkvb)
    //   Vt     @40 MB     8 MB
    //   Ob     @16 MB     8 MB  (over dead qkv)
    //   wprojb @24 MB     2 MB  (over dead qkv)
    char* ws = (char*)d_ws;
    unsigned short* xb     = (unsigned short*)(ws);
    unsigned short* wqkvb  = (unsigned short*)(ws + 8388608ull);
    unsigned short* qkv    = (unsigned short*)(ws + 16777216ull);
    unsigned short* Qb     = (unsigned short*)(ws);
    unsigned short* Kb     = (unsigned short*)(ws + 8388608ull);
    unsigned short* Vb     = (unsigned short*)(ws + 41943040ull);
    unsigned short* Ob     = (unsigned short*)(ws + 16777216ull);
    unsigned short* wprojb = (unsigned short*)(ws + 25165824ull);

    // 0) convert x (1048576 f4) + w_qkv (786432 f4) to bf16
    cvt2<<<dim3(1792), 256, 0, stream>>>(x, xb, 1048576, w_qkv, wqkvb, 786432);
    // 1) qkv = x @ w_qkv^T   M=4096 N=3072 K=1024
    gemm_bt<false><<<dim3(24, 32), 256, 0, stream>>>(xb, wqkvb, nullptr, qkv, 3072, 1024, 0);
    // 2) RMSNorm + RoPE, split heads, transpose V
    norm_rope<<<dim3(16384), 256, 0, stream>>>(qkv, fc, fs, qg, kg, Qb, Kb, Vb);
    // 2b) convert w_proj (262144 f4) into dead qkv region
    cvt2<<<dim3(512), 256, 0, stream>>>(w_proj, wprojb, 262144, nullptr, nullptr, 0);
    // 3) flash attention -> Ob [b][n][C] bf16
    attn<<<dim3(32, 32), 256, 0, stream>>>(Qb, Kb, Vb, mask, Ob);
    // 4) out = Ob @ w_proj^T + b   M=4096 N=1024 K=1024, fp32 out
    gemm_bt<true><<<dim3(8, 32), 256, 0, stream>>>(Ob, wprojb, b_proj, d_out, 1024, 1024, 1);
}

// Round 5
// 286.596 us; speedup vs baseline: 1.3910x; 1.3910x over previous
//
#include <hip/hip_runtime.h>
#include <hip/hip_bf16.h>

// Problem constants: B=2, N=2048, C=1024, H=16, hd=64. All inputs/output fp32.
#define SEQ   2048
#define CDIM  1024

typedef short short8  __attribute__((ext_vector_type(8)));
typedef short short4v __attribute__((ext_vector_type(4)));
typedef float floatx4 __attribute__((ext_vector_type(4)));

__device__ __forceinline__ float bf2f(unsigned short h) {
    unsigned int u = ((unsigned int)h) << 16;
    float f; __builtin_memcpy(&f, &u, 4); return f;
}
__device__ __forceinline__ unsigned short f2bf(float f) {
    unsigned int u; __builtin_memcpy(&u, &f, 4);
    u += 0x7fffu + ((u >> 16) & 1u);   // RNE
    return (unsigned short)(u >> 16);
}

// ---------------------------------------------------------------------------
// fp32 -> bf16 conversion, two arrays per launch (second may be empty).
// ---------------------------------------------------------------------------
__global__ __launch_bounds__(256) void cvt2(
    const float* __restrict__ a, unsigned short* __restrict__ da, int na4,
    const float* __restrict__ b, unsigned short* __restrict__ db, int nb4)
{
    int total = na4 + nb4;
    for (int i = blockIdx.x * 256 + threadIdx.x; i < total; i += gridDim.x * 256) {
        const float* src; unsigned short* dst; int j;
        if (i < na4) { src = a; dst = da; j = i; }
        else         { src = b; dst = db; j = i - na4; }
        floatx4 v = ((const floatx4*)src)[j];
        short4v o;
        o[0] = f2bf(v[0]); o[1] = f2bf(v[1]); o[2] = f2bf(v[2]); o[3] = f2bf(v[3]);
        ((short4v*)dst)[j] = o;
    }
}

// ---------------------------------------------------------------------------
// GEMM: C[m][n] = sum_k A[m][k]*B[n][k] (+bias[n]). bf16 in, fp32 acc.
// m97 structure: 128x128 tile, BK=32, unpadded LDS, global_load_lds width=16.
// ---------------------------------------------------------------------------
template <bool OUT_F32>
__global__ __launch_bounds__(256) void gemm_bt(
    const unsigned short* __restrict__ A,
    const unsigned short* __restrict__ B,
    const float* __restrict__ bias,
    void* __restrict__ C,
    int Ndim, int Kdim, int use_bias)
{
    __shared__ unsigned short As[128][32];
    __shared__ unsigned short Bs[128][32];

    const int tid  = threadIdx.x;
    const int lane = tid & 63, wave = tid >> 6;
    const int wr = (wave >> 1) * 64, wc = (wave & 1) * 64;
    const int lrow = lane & 15, quad = lane >> 4;
    const int m0 = blockIdx.y * 128, n0 = blockIdx.x * 128;

    const int ako = (lane & 3) * 8;            // k-offset within BK for staging
    floatx4 acc[4][4] = {};

    for (int k0 = 0; k0 < Kdim; k0 += 32) {
        __syncthreads();
        #pragma unroll
        for (int j = 0; j < 2; ++j) {
            int rbase = (wave * 2 + j) * 16;
            int row   = rbase + (lane >> 2);
            __builtin_amdgcn_global_load_lds(
                (const __attribute__((address_space(1))) void*)(A + (size_t)(m0 + row) * Kdim + k0 + ako),
                (__attribute__((address_space(3))) void*)&As[rbase][0], 16, 0, 0);
            __builtin_amdgcn_global_load_lds(
                (const __attribute__((address_space(1))) void*)(B + (size_t)(n0 + row) * Kdim + k0 + ako),
                (__attribute__((address_space(3))) void*)&Bs[rbase][0], 16, 0, 0);
        }
        __syncthreads();   // drains vmcnt(0) -> LDS valid

        short8 af[4], bf[4];
        #pragma unroll
        for (int mi = 0; mi < 4; ++mi) af[mi] = *(const short8*)&As[wr + mi * 16 + lrow][quad * 8];
        #pragma unroll
        for (int ni = 0; ni < 4; ++ni) bf[ni] = *(const short8*)&Bs[wc + ni * 16 + lrow][quad * 8];
        #pragma unroll
        for (int mi = 0; mi < 4; ++mi)
            #pragma unroll
            for (int ni = 0; ni < 4; ++ni)
                acc[mi][ni] = __builtin_amdgcn_mfma_f32_16x16x32_bf16(af[mi], bf[ni], acc[mi][ni], 0, 0, 0);
    }

    // C/D layout: col = lane&15, row = quad*4 + r
    #pragma unroll
    for (int mi = 0; mi < 4; ++mi) {
        #pragma unroll
        for (int r = 0; r < 4; ++r) {
            int row = m0 + wr + mi * 16 + quad * 4 + r;
            #pragma unroll
            for (int ni = 0; ni < 4; ++ni) {
                int col = n0 + wc + ni * 16 + lrow;
                float v = acc[mi][ni][r];
                if (use_bias) v += bias[col];
                if (OUT_F32) ((float*)C)[(size_t)row * Ndim + col] = v;
                else ((unsigned short*)C)[(size_t)row * Ndim + col] = f2bf(v);
            }
        }
    }
}

// ---------------------------------------------------------------------------
// Per-(token,head) RMSNorm + RoPE for Q,K only. One wave per (m,h), lane=dim.
// (V handled by vtrans — no norm/RoPE needed, avoids the 2B/4KB-stride scatter.)
// ---------------------------------------------------------------------------
__global__ __launch_bounds__(256) void norm_rope(
    const unsigned short* __restrict__ qkv,
    const float* __restrict__ fc,
    const float* __restrict__ fs,
    const float* __restrict__ qg,
    const float* __restrict__ kg,
    unsigned short* __restrict__ Q,
    unsigned short* __restrict__ K)
{
    int gid  = blockIdx.x * 4 + (threadIdx.x >> 6);
    int lane = threadIdx.x & 63;
    int h = gid & 15, m = gid >> 4;
    int b = m >> 11, n = m & 2047;

    const unsigned short* row = qkv + (size_t)m * 3072;
    float q = bf2f(row[h * 64 + lane]);
    float k = bf2f(row[1024 + h * 64 + lane]);

    float q2 = q * q, k2 = k * k;
    #pragma unroll
    for (int off = 32; off; off >>= 1) {
        q2 += __shfl_xor(q2, off);
        k2 += __shfl_xor(k2, off);
    }
    q = q * (8.0f / fmaxf(sqrtf(q2), 1e-12f)) * qg[lane];
    k = k * (8.0f / fmaxf(sqrtf(k2), 1e-12f)) * kg[lane];

    float c = fc[(size_t)m * 64 + lane];
    float s = fs[(size_t)m * 64 + lane];
    float qp = __shfl_xor(q, 1), kp = __shfl_xor(k, 1);
    float qr = (lane & 1) ? qp : -qp;
    float kr = (lane & 1) ? kp : -kp;
    q = q * c + qr * s;
    k = k * c + kr * s;

    int bh = b * 16 + h;
    Q[((size_t)bh * SEQ + n) * 64 + lane] = f2bf(q);
    K[((size_t)bh * SEQ + n) * 64 + lane] = f2bf(k);
}

// ---------------------------------------------------------------------------
// V transpose: qkv[m][2048 + h*64 + d] -> Vt[bh][d][n]. LDS-tiled so both
// global read and write are >=128B coalesced. Block = (128 tokens, one bh).
// ---------------------------------------------------------------------------
__global__ __launch_bounds__(256) void vtrans(
    const unsigned short* __restrict__ qkv,
    unsigned short* __restrict__ Vt)
{
    __shared__ unsigned short T[64][136];   // [d][t], +8 pad
    const int tid = threadIdx.x;
    const int bh = blockIdx.y, b = bh >> 4, h = bh & 15;
    const int n0 = blockIdx.x * 128;

    #pragma unroll
    for (int i = 0; i < 4; ++i) {           // 128 tokens x 8 d-chunks
        int u = tid + i * 256;
        int t = u >> 3, dc = (u & 7) * 8;
        short8 v = *(const short8*)(qkv + (size_t)(b * 2048 + n0 + t) * 3072 + 2048 + h * 64 + dc);
        #pragma unroll
        for (int j = 0; j < 8; ++j) T[dc + j][t] = v[j];
    }
    __syncthreads();
    #pragma unroll
    for (int i = 0; i < 4; ++i) {           // 64 d x 16 t-chunks
        int u = tid + i * 256;
        int d = u >> 4, tc = (u & 15) * 8;
        *(short8*)(Vt + ((size_t)bh * 64 + d) * SEQ + n0 + tc) = *(const short8*)&T[d][tc];
    }
}

// ---------------------------------------------------------------------------
// Flash attention, S^T formulation, 64-key tiles (r3 LDS footprint + r4 VALU
// savings). Block = (qt, bh): 64 q-rows, 4 waves each owning 16 q-rows.
// mfma(kf, qf) -> lane holds S^T[key=ni*16+quad*4+r][q=q0w+(lane&15)]:
// softmax reductions are in-lane + 2 shfl_xor; mask loads are float4.
// ---------------------------------------------------------------------------
__global__ __launch_bounds__(256) void attn(
    const unsigned short* __restrict__ Q,
    const unsigned short* __restrict__ K,
    const unsigned short* __restrict__ Vt,
    const float* __restrict__ mask,
    unsigned short* __restrict__ O)
{
    __shared__ unsigned short Ks[64][72];     // [key][d], +8 pad
    __shared__ unsigned short Vs[64][72];     // [d][key], +8 pad
    __shared__ unsigned short Ps[4][16][72];  // per-wave P, [q][key], +8 pad

    const int tid = threadIdx.x, lane = tid & 63, wave = tid >> 6;
    const int lrow = lane & 15, quad = lane >> 4;
    const int qt = blockIdx.x, bh = blockIdx.y;
    const int b = bh >> 4, h = bh & 15;
    const int q0 = qt * 64 + wave * 16;
    const float scale = 0.125f;   // 64^-0.5

    const unsigned short* Qb = Q + (size_t)bh * SEQ * 64;
    const unsigned short* Kb = K + (size_t)bh * SEQ * 64;
    const unsigned short* Vb = Vt + (size_t)bh * 64 * SEQ;
    const float* mrow = mask + (size_t)(q0 + lrow) * SEQ;   // this lane's q-row

    // Q frags (B-operand): [n=lane&15=q][k=quad*8+j], two 32-wide k-steps
    short8 qf[2];
    #pragma unroll
    for (int ks = 0; ks < 2; ++ks)
        qf[ks] = *(const short8*)(Qb + (size_t)(q0 + lrow) * 64 + ks * 32 + quad * 8);

    float m_i = -1e30f, l_i = 0.f;
    floatx4 oacc[4] = {};

    for (int kt = 0; kt < 32; ++kt) {
        __syncthreads();
        #pragma unroll
        for (int i = 0; i < 2; ++i) {          // Ks: 512 chunks of 8 bf16
            int c = tid + i * 256;
            int kr = c >> 3, ko = (c & 7) * 8;
            *(short8*)&Ks[kr][ko] = *(const short8*)(Kb + (size_t)(kt * 64 + kr) * 64 + ko);
        }
        #pragma unroll
        for (int i = 0; i < 2; ++i) {          // Vs: 512 chunks of 8 bf16
            int c = tid + i * 256;
            int vr = c >> 3, ko = (c & 7) * 8;
            *(short8*)&Vs[vr][ko] = *(const short8*)(Vb + (size_t)vr * SEQ + kt * 64 + ko);
        }
        __syncthreads();

        // S^T = K @ Q^T : s[ni][r] = S[key=ni*16+quad*4+r][q=q0+lrow]
        floatx4 s[4];
        #pragma unroll
        for (int ni = 0; ni < 4; ++ni) {
            s[ni] = floatx4{0.f, 0.f, 0.f, 0.f};
            #pragma unroll
            for (int ks = 0; ks < 2; ++ks) {
                short8 kf = *(const short8*)&Ks[ni * 16 + lrow][ks * 32 + quad * 8];
                s[ni] = __builtin_amdgcn_mfma_f32_16x16x32_bf16(kf, qf[ks], s[ni], 0, 0, 0);
            }
        }

        // scale + mask (float4: 4 consecutive keys per lane)
        float mt = -1e30f;
        #pragma unroll
        for (int ni = 0; ni < 4; ++ni) {
            floatx4 mk = *(const floatx4*)(mrow + kt * 64 + ni * 16 + quad * 4);
            #pragma unroll
            for (int r = 0; r < 4; ++r) {
                s[ni][r] = s[ni][r] * scale + mk[r];
                mt = fmaxf(mt, s[ni][r]);
            }
        }
        mt = fmaxf(mt, __shfl_xor(mt, 16));
        mt = fmaxf(mt, __shfl_xor(mt, 32));

        float mn = fmaxf(m_i, mt);
        float alpha = __expf(m_i - mn);
        m_i = mn;
        float rs = 0.f;
        #pragma unroll
        for (int ni = 0; ni < 4; ++ni)
            #pragma unroll
            for (int r = 0; r < 4; ++r) {
                float p = __expf(s[ni][r] - mn);
                s[ni][r] = p;
                rs += p;
            }
        rs += __shfl_xor(rs, 16);
        rs += __shfl_xor(rs, 32);
        l_i = l_i * alpha + rs;

        // P^T -> LDS [q][key], b64 packed (4 consecutive keys per lane)
        #pragma unroll
        for (int ni = 0; ni < 4; ++ni) {
            short4v pk;
            pk[0] = f2bf(s[ni][0]); pk[1] = f2bf(s[ni][1]);
            pk[2] = f2bf(s[ni][2]); pk[3] = f2bf(s[ni][3]);
            *(short4v*)&Ps[wave][lrow][ni * 16 + quad * 4] = pk;
        }

        // rescale O rows (q = q0+quad*4+r; alpha uniform across quads of a
        // given lrow, so lane quad*4+r holds row's alpha)
        #pragma unroll
        for (int r = 0; r < 4; ++r) {
            float ar = __shfl(alpha, quad * 4 + r);
            #pragma unroll
            for (int ni = 0; ni < 4; ++ni) oacc[ni][r] *= ar;
        }

        // O += P @ V. Ps is wave-private: in-wave lgkmcnt ordering, no barrier.
        short8 pa[2];
        #pragma unroll
        for (int ks = 0; ks < 2; ++ks)
            pa[ks] = *(const short8*)&Ps[wave][lrow][ks * 32 + quad * 8];
        #pragma unroll
        for (int ni = 0; ni < 4; ++ni)
            #pragma unroll
            for (int ks = 0; ks < 2; ++ks) {
                short8 vb = *(const short8*)&Vs[ni * 16 + lrow][ks * 32 + quad * 8];
                oacc[ni] = __builtin_amdgcn_mfma_f32_16x16x32_bf16(pa[ks], vb, oacc[ni], 0, 0, 0);
            }
    }

    // epilogue: denom for row q0+quad*4+r lives at lane quad*4+r
    float inv[4];
    #pragma unroll
    for (int r = 0; r < 4; ++r) inv[r] = 1.0f / __shfl(l_i, quad * 4 + r);
    #pragma unroll
    for (int r = 0; r < 4; ++r) {
        int row = q0 + quad * 4 + r;
        #pragma unroll
        for (int ni = 0; ni < 4; ++ni) {
            int col = ni * 16 + lrow;
            O[((size_t)(b * SEQ + row)) * CDIM + h * 64 + col] = f2bf(oacc[ni][r] * inv[r]);
        }
    }
}

// ---------------------------------------------------------------------------
extern "C" void kernel_launch(void* const* d_in, const int* in_sizes, int n_in,
                              void* d_out, int out_size, void* d_ws, size_t ws_size,
                              hipStream_t stream)
{
    const float* x      = (const float*)d_in[0];
    const float* fc     = (const float*)d_in[1];
    const float* fs     = (const float*)d_in[2];
    const float* mask   = (const float*)d_in[3];
    const float* w_qkv  = (const float*)d_in[4];
    const float* w_proj = (const float*)d_in[5];
    const float* b_proj = (const float*)d_in[6];
    const float* qg     = (const float*)d_in[7];
    const float* kg     = (const float*)d_in[8];

    // workspace (48 MB high-water):
    //   xb     @0         8 MB  (x bf16)          dead after gemm1
    //   wqkvb  @8 MB      6 MB  (w_qkv bf16)      dead after gemm1
    //   qkv    @16 MB    24 MB  (gemm1 out)       dead after vtrans
    //   Q      @0         8 MB  (over dead xb)
    //   K      @8 MB      8 MB  (over dead wqkvb)
    //   Vt     @40 MB     8 MB
    //   Ob     @16 MB     8 MB  (over dead qkv)
    //   wprojb @24 MB     2 MB  (over dead qkv)
    char* ws = (char*)d_ws;
    unsigned short* xb     = (unsigned short*)(ws);
    unsigned short* wqkvb  = (unsigned short*)(ws + 8388608ull);
    unsigned short* qkv    = (unsigned short*)(ws + 16777216ull);
    unsigned short* Qb     = (unsigned short*)(ws);
    unsigned short* Kb     = (unsigned short*)(ws + 8388608ull);
    unsigned short* Vb     = (unsigned short*)(ws + 41943040ull);
    unsigned short* Ob     = (unsigned short*)(ws + 16777216ull);
    unsigned short* wprojb = (unsigned short*)(ws + 25165824ull);

    // 0) convert x (1048576 f4) + w_qkv (786432 f4) to bf16
    cvt2<<<dim3(1792), 256, 0, stream>>>(x, xb, 1048576, w_qkv, wqkvb, 786432);
    // 1) qkv = x @ w_qkv^T   M=4096 N=3072 K=1024
    gemm_bt<false><<<dim3(24, 32), 256, 0, stream>>>(xb, wqkvb, nullptr, qkv, 3072, 1024, 0);
    // 2) RMSNorm + RoPE (Q,K) ; V transpose
    norm_rope<<<dim3(16384), 256, 0, stream>>>(qkv, fc, fs, qg, kg, Qb, Kb);
    vtrans<<<dim3(16, 32), 256, 0, stream>>>(qkv, Vb);
    // 2b) convert w_proj (262144 f4)
    cvt2<<<dim3(512), 256, 0, stream>>>(w_proj, wprojb, 262144, nullptr, nullptr, 0);
    // 3) flash attention -> Ob [b][n][C] bf16
    attn<<<dim3(32, 32), 256, 0, stream>>>(Qb, Kb, Vb, mask, Ob);
    // 4) out = Ob @ w_proj^T + b   M=4096 N=1024 K=1024, fp32 out
    gemm_bt<true><<<dim3(8, 32), 256, 0, stream>>>(Ob, wprojb, b_proj, d_out, 1024, 1024, 1);
}